// Round 1
// baseline (752.456 us; speedup 1.0000x reference)
//
#include <hip/hip_runtime.h>
#include <math.h>

#define N_ANCHOR   900
#define NUM_CAMS   6
#define CDIM       256
#define NUM_LEVELS 4
#define NUM_FIXED  7
#define NUM_LEARN  6
#define NUM_PTS    13
#define NUM_GROUPS 8
#define NW         2496   // NUM_CAMS*NUM_LEVELS*NUM_PTS*NUM_GROUPS
#define NI         312    // NUM_CAMS*NUM_LEVELS*NUM_PTS (softmax axis)
#define SUM_HW     14960
#define AT         4      // anchors per block in weights kernel (900 % 4 == 0)

// ---------------------------------------------------------------------------
// Kernel 1: keypoints + camera projection.
// grid = 900 (one block per anchor), block = 128
// ---------------------------------------------------------------------------
__global__ __launch_bounds__(128) void k_prep(
    const float* __restrict__ inst, const float* __restrict__ anchor,
    const float* __restrict__ l2i, const float* __restrict__ image_wh,
    const float* __restrict__ kp_fixed, const float* __restrict__ kp_w,
    const float* __restrict__ kp_b,
    float* __restrict__ pts_out, float* __restrict__ valid_out) {
  const int n = blockIdx.x;
  const int t = threadIdx.x;
  __shared__ float anc[11];
  __shared__ float learn[NUM_LEARN * 3];
  __shared__ float kps[NUM_PTS][3];

  if (t < 11) anc[t] = anchor[n * 11 + t];
  if (t < NUM_LEARN * 3) {
    // learn = inst[n] @ kp_w + kp_b   (kp_w is (256,18) row-major)
    float s = kp_b[t];
    const float* ip = inst + n * CDIM;
    for (int k = 0; k < CDIM; ++k) s += ip[k] * kp_w[k * (NUM_LEARN * 3) + t];
    learn[t] = s;
  }
  __syncthreads();

  if (t < NUM_PTS) {
    const float sx = expf(anc[3]), sy = expf(anc[4]), sz = expf(anc[5]);
    float ox, oy, oz;
    if (t < NUM_FIXED) {
      ox = kp_fixed[t * 3 + 0]; oy = kp_fixed[t * 3 + 1]; oz = kp_fixed[t * 3 + 2];
    } else {
      const int j = (t - NUM_FIXED) * 3;
      ox = learn[j + 0]; oy = learn[j + 1]; oz = learn[j + 2];
    }
    ox *= sx; oy *= sy; oz *= sz;
    const float sn = anc[6], cs = anc[7];
    kps[t][0] = cs * ox - sn * oy + anc[0];
    kps[t][1] = sn * ox + cs * oy + anc[1];
    kps[t][2] = oz + anc[2];
  }
  __syncthreads();

  if (t < NUM_CAMS * NUM_PTS) {
    const int cam = t / NUM_PTS, p = t % NUM_PTS;
    const float* M = l2i + cam * 16;
    const float kx = kps[p][0], ky = kps[p][1], kz = kps[p][2];
    const float px = M[0] * kx + M[1] * ky + M[2]  * kz + M[3];
    const float py = M[4] * kx + M[5] * ky + M[6]  * kz + M[7];
    const float pz = M[8] * kx + M[9] * ky + M[10] * kz + M[11];
    const float d = fmaxf(pz, 1e-5f);
    const float u = (px / d) / image_wh[cam * 2 + 0];
    const float v = (py / d) / image_wh[cam * 2 + 1];
    const int o = n * NUM_CAMS * NUM_PTS + t;
    pts_out[o * 2 + 0] = u;
    pts_out[o * 2 + 1] = v;
    valid_out[o] = (pz > 1e-5f) ? 1.0f : 0.0f;
  }
}

// ---------------------------------------------------------------------------
// Kernel 2: anchor_embed, wfc GEMM (900x2496x256), per-group softmax.
// grid = 900/AT, block = 256. Each block: AT anchors, reusing wfc_w loads.
// ---------------------------------------------------------------------------
__global__ __launch_bounds__(256) void k_weights(
    const float* __restrict__ inst, const float* __restrict__ anchor,
    const float* __restrict__ enc_w, const float* __restrict__ enc_b,
    const float* __restrict__ wfc_w, const float* __restrict__ wfc_b,
    float* __restrict__ w_out) {
  const int t = threadIdx.x;
  const int n0 = blockIdx.x * AT;
  __shared__ float q[AT][CDIM];
  __shared__ float raw[AT][NW];          // 40 KB
  __shared__ float mx[AT][NUM_GROUPS];
  __shared__ float sminv[AT][NUM_GROUPS];

  // q = inst + anchor @ enc_w + enc_b
  for (int a = 0; a < AT; ++a) {
    const int n = n0 + a;
    float s = enc_b[t] + inst[n * CDIM + t];
    #pragma unroll
    for (int k = 0; k < 11; ++k) s += anchor[n * 11 + k] * enc_w[k * CDIM + t];
    q[a][t] = s;
  }
  __syncthreads();

  float acc[AT][10];
  #pragma unroll
  for (int a = 0; a < AT; ++a)
    #pragma unroll
    for (int u = 0; u < 10; ++u) acc[a][u] = 0.0f;

  for (int k = 0; k < CDIM; ++k) {
    const float q0 = q[0][k], q1 = q[1][k], q2 = q[2][k], q3 = q[3][k];
    const float* wrow = wfc_w + (size_t)k * NW;
    #pragma unroll
    for (int u = 0; u < 10; ++u) {
      const int j = t + u * 256;
      if (j < NW) {
        const float wv = wrow[j];
        acc[0][u] += q0 * wv;
        acc[1][u] += q1 * wv;
        acc[2][u] += q2 * wv;
        acc[3][u] += q3 * wv;
      }
    }
  }
  #pragma unroll
  for (int a = 0; a < AT; ++a)
    #pragma unroll
    for (int u = 0; u < 10; ++u) {
      const int j = t + u * 256;
      if (j < NW) raw[a][j] = acc[a][u] + wfc_b[j];
    }
  __syncthreads();

  // softmax over the 312 entries of each (anchor, group)
  if (t < AT * NUM_GROUPS) {
    const int a = t / NUM_GROUPS, g = t % NUM_GROUPS;
    float m = -1e30f;
    for (int i = 0; i < NI; ++i) m = fmaxf(m, raw[a][i * NUM_GROUPS + g]);
    float s = 0.0f;
    for (int i = 0; i < NI; ++i) s += expf(raw[a][i * NUM_GROUPS + g] - m);
    mx[a][g] = m;
    sminv[a][g] = 1.0f / s;
  }
  __syncthreads();

  for (int a = 0; a < AT; ++a)
    #pragma unroll
    for (int u = 0; u < 10; ++u) {
      const int j = t + u * 256;
      if (j < NW) {
        const int g = j & 7;
        w_out[(size_t)(n0 + a) * NW + j] = expf(raw[a][j] - mx[a][g]) * sminv[a][g];
      }
    }
}

// ---------------------------------------------------------------------------
// Kernel 3: fused bilinear sampling + weighted aggregation.
// grid = 900 (one block per anchor), block = 256 (thread = channel).
// ---------------------------------------------------------------------------
__global__ __launch_bounds__(256) void k_sample(
    const float* __restrict__ feature,
    const int* __restrict__ spatial_shapes, const int* __restrict__ level_start,
    const float* __restrict__ pts, const float* __restrict__ valid,
    const float* __restrict__ w, float* __restrict__ agg) {
  const int n = blockIdx.x;
  const int t = threadIdx.x;
  const int g = t >> 5;  // group = channel / 32
  __shared__ float w_s[NW];
  __shared__ float uv_s[NUM_CAMS * NUM_PTS][2];
  __shared__ float val_s[NUM_CAMS * NUM_PTS];
  __shared__ int shp[NUM_LEVELS][2];
  __shared__ int lst[NUM_LEVELS];

  for (int j = t; j < NW; j += 256) w_s[j] = w[(size_t)n * NW + j];
  if (t < NUM_CAMS * NUM_PTS) {
    const int o = n * NUM_CAMS * NUM_PTS + t;
    uv_s[t][0] = pts[o * 2 + 0];
    uv_s[t][1] = pts[o * 2 + 1];
    val_s[t] = valid[o];
  }
  if (t < NUM_LEVELS) {
    shp[t][0] = spatial_shapes[t * 2 + 0];
    shp[t][1] = spatial_shapes[t * 2 + 1];
    lst[t] = level_start[t];
  }
  __syncthreads();

  float acc = 0.0f;
  for (int cam = 0; cam < NUM_CAMS; ++cam) {
    const float* fcam = feature + (size_t)cam * SUM_HW * CDIM;
    for (int p = 0; p < NUM_PTS; ++p) {
      const int cp = cam * NUM_PTS + p;
      if (val_s[cp] == 0.0f) continue;    // wave-uniform: same for whole block
      const float u = uv_s[cp][0], v = uv_s[cp][1];
      #pragma unroll
      for (int l = 0; l < NUM_LEVELS; ++l) {
        const int H = shp[l][0], W = shp[l][1], st = lst[l];
        const float x = u * (float)W - 0.5f;
        const float y = v * (float)H - 0.5f;
        const float x0f = floorf(x), y0f = floorf(y);
        const int x0 = (int)x0f, y0 = (int)y0f;
        const float wx = x - x0f, wy = y - y0f;
        const float wgt = w_s[(cam * 52 + l * 13 + p) * 8 + g];
        const bool xin0 = (x0 >= 0) && (x0 < W);
        const bool xin1 = (x0 + 1 >= 0) && (x0 + 1 < W);
        const bool yin0 = (y0 >= 0) && (y0 < H);
        const bool yin1 = (y0 + 1 >= 0) && (y0 + 1 < H);
        const float c00 = wgt * (1.0f - wx) * (1.0f - wy);
        const float c10 = wgt * wx * (1.0f - wy);
        const float c01 = wgt * (1.0f - wx) * wy;
        const float c11 = wgt * wx * wy;
        const float* base = fcam + (size_t)st * CDIM + t;
        if (xin0 && yin0) acc += c00 * base[(size_t)(y0 * W + x0) * CDIM];
        if (xin1 && yin0) acc += c10 * base[(size_t)(y0 * W + x0 + 1) * CDIM];
        if (xin0 && yin1) acc += c01 * base[(size_t)((y0 + 1) * W + x0) * CDIM];
        if (xin1 && yin1) acc += c11 * base[(size_t)((y0 + 1) * W + x0 + 1) * CDIM];
      }
    }
  }
  agg[(size_t)n * CDIM + t] = acc;
}

// ---------------------------------------------------------------------------
// Kernel 4: out = inst + agg @ out_w + out_b
// grid = 900, block = 256 (thread = output channel).
// ---------------------------------------------------------------------------
__global__ __launch_bounds__(256) void k_out(
    const float* __restrict__ inst, const float* __restrict__ agg,
    const float* __restrict__ out_w, const float* __restrict__ out_b,
    float* __restrict__ out) {
  const int n = blockIdx.x, t = threadIdx.x;
  __shared__ float a_s[CDIM];
  a_s[t] = agg[(size_t)n * CDIM + t];
  __syncthreads();
  float s = out_b[t] + inst[(size_t)n * CDIM + t];
  for (int k = 0; k < CDIM; ++k) s += a_s[k] * out_w[k * CDIM + t];
  out[(size_t)n * CDIM + t] = s;
}

// ---------------------------------------------------------------------------
extern "C" void kernel_launch(void* const* d_in, const int* in_sizes, int n_in,
                              void* d_out, int out_size, void* d_ws, size_t ws_size,
                              hipStream_t stream) {
  const float* inst          = (const float*)d_in[0];
  const float* anchor        = (const float*)d_in[1];
  // d_in[2] time_interval: unused
  const float* feature       = (const float*)d_in[3];
  const int*   spatial_shapes= (const int*)d_in[4];
  const int*   level_start   = (const int*)d_in[5];
  const float* l2i           = (const float*)d_in[6];
  const float* image_wh      = (const float*)d_in[7];
  const float* enc_w         = (const float*)d_in[8];
  const float* enc_b         = (const float*)d_in[9];
  const float* kp_fixed      = (const float*)d_in[10];
  const float* kp_w          = (const float*)d_in[11];
  const float* kp_b          = (const float*)d_in[12];
  const float* wfc_w         = (const float*)d_in[13];
  const float* wfc_b         = (const float*)d_in[14];
  const float* out_w         = (const float*)d_in[15];
  const float* out_b         = (const float*)d_in[16];

  float* ws    = (float*)d_ws;
  float* pts   = ws;                                          // 900*6*13*2
  float* valid = pts + N_ANCHOR * NUM_CAMS * NUM_PTS * 2;     // 900*6*13
  float* wbuf  = valid + N_ANCHOR * NUM_CAMS * NUM_PTS;       // 900*2496
  float* agg   = wbuf + (size_t)N_ANCHOR * NW;                // 900*256

  k_prep<<<N_ANCHOR, 128, 0, stream>>>(inst, anchor, l2i, image_wh,
                                       kp_fixed, kp_w, kp_b, pts, valid);
  k_weights<<<N_ANCHOR / AT, 256, 0, stream>>>(inst, anchor, enc_w, enc_b,
                                               wfc_w, wfc_b, wbuf);
  k_sample<<<N_ANCHOR, 256, 0, stream>>>(feature, spatial_shapes, level_start,
                                         pts, valid, wbuf, agg);
  k_out<<<N_ANCHOR, 256, 0, stream>>>(inst, agg, out_w, out_b, (float*)d_out);
}

// Round 2
// 314.418 us; speedup vs baseline: 2.3932x; 2.3932x over previous
//
#include <hip/hip_runtime.h>
#include <math.h>

#define N_ANCHOR   900
#define NUM_CAMS   6
#define CDIM       256
#define NUM_LEVELS 4
#define NUM_FIXED  7
#define NUM_LEARN  6
#define NUM_PTS    13
#define NUM_GROUPS 8
#define NW         2496   // NUM_CAMS*NUM_LEVELS*NUM_PTS*NUM_GROUPS
#define NI         312    // NUM_CAMS*NUM_LEVELS*NUM_PTS (softmax axis)
#define SUM_HW     14960

// ---------------------------------------------------------------------------
// Kernel 1: keypoints + camera projection.  grid = 900, block = 128
// ---------------------------------------------------------------------------
__global__ __launch_bounds__(128) void k_prep(
    const float* __restrict__ inst, const float* __restrict__ anchor,
    const float* __restrict__ l2i, const float* __restrict__ image_wh,
    const float* __restrict__ kp_fixed, const float* __restrict__ kp_w,
    const float* __restrict__ kp_b,
    float* __restrict__ pts_out, float* __restrict__ valid_out) {
  const int n = blockIdx.x;
  const int t = threadIdx.x;
  __shared__ float anc[11];
  __shared__ float learn[NUM_LEARN * 3];
  __shared__ float kps[NUM_PTS][3];
  __shared__ float ins[CDIM];

  ins[t] = inst[n * CDIM + t];
  ins[t + 128] = inst[n * CDIM + t + 128];
  if (t < 11) anc[t] = anchor[n * 11 + t];
  __syncthreads();
  if (t < NUM_LEARN * 3) {
    float s = kp_b[t];
    for (int k = 0; k < CDIM; ++k) s += ins[k] * kp_w[k * (NUM_LEARN * 3) + t];
    learn[t] = s;
  }
  __syncthreads();

  if (t < NUM_PTS) {
    const float sx = expf(anc[3]), sy = expf(anc[4]), sz = expf(anc[5]);
    float ox, oy, oz;
    if (t < NUM_FIXED) {
      ox = kp_fixed[t * 3 + 0]; oy = kp_fixed[t * 3 + 1]; oz = kp_fixed[t * 3 + 2];
    } else {
      const int j = (t - NUM_FIXED) * 3;
      ox = learn[j + 0]; oy = learn[j + 1]; oz = learn[j + 2];
    }
    ox *= sx; oy *= sy; oz *= sz;
    const float sn = anc[6], cs = anc[7];
    kps[t][0] = cs * ox - sn * oy + anc[0];
    kps[t][1] = sn * ox + cs * oy + anc[1];
    kps[t][2] = oz + anc[2];
  }
  __syncthreads();

  if (t < NUM_CAMS * NUM_PTS) {
    const int cam = t / NUM_PTS, p = t % NUM_PTS;
    const float* M = l2i + cam * 16;
    const float kx = kps[p][0], ky = kps[p][1], kz = kps[p][2];
    const float px = M[0] * kx + M[1] * ky + M[2]  * kz + M[3];
    const float py = M[4] * kx + M[5] * ky + M[6]  * kz + M[7];
    const float pz = M[8] * kx + M[9] * ky + M[10] * kz + M[11];
    const float d = fmaxf(pz, 1e-5f);
    const float u = (px / d) / image_wh[cam * 2 + 0];
    const float v = (py / d) / image_wh[cam * 2 + 1];
    const int o = n * NUM_CAMS * NUM_PTS + t;
    pts_out[o * 2 + 0] = u;
    pts_out[o * 2 + 1] = v;
    valid_out[o] = (pz > 1e-5f) ? 1.0f : 0.0f;
  }
}

// ---------------------------------------------------------------------------
// Kernel 2a: q = inst + anchor @ enc_w + enc_b.  grid = 900, block = 256
// ---------------------------------------------------------------------------
__global__ __launch_bounds__(256) void k_embed(
    const float* __restrict__ inst, const float* __restrict__ anchor,
    const float* __restrict__ enc_w, const float* __restrict__ enc_b,
    float* __restrict__ q) {
  const int n = blockIdx.x, t = threadIdx.x;
  float s = enc_b[t] + inst[n * CDIM + t];
  #pragma unroll
  for (int k = 0; k < 11; ++k) s += anchor[n * 11 + k] * enc_w[k * CDIM + t];
  q[n * CDIM + t] = s;
}

// ---------------------------------------------------------------------------
// Kernel 2b: tiled GEMM  raw[900][2496] = q[900][256] @ wfc_w[256][2496] + b
// 64x64 tile, 4x4 per thread, K-tile 16. grid = (39, 15), block = 256.
// ---------------------------------------------------------------------------
__global__ __launch_bounds__(256) void k_wgemm(
    const float* __restrict__ q, const float* __restrict__ wfc_w,
    const float* __restrict__ wfc_b, float* __restrict__ raw) {
  const int tid = threadIdx.x;
  const int n0 = blockIdx.x * 64;
  const int m0 = blockIdx.y * 64;
  const int tx = tid & 15, ty = tid >> 4;
  __shared__ float AsT[16][68];   // [k][row], stride 68 keeps 16B align + banks spread
  __shared__ float Bs[16][64];    // [k][col]
  float acc[4][4] = {{0.f}};

  for (int k0 = 0; k0 < CDIM; k0 += 16) {
    #pragma unroll
    for (int i = 0; i < 4; ++i) {
      const int idx = tid + i * 256;
      const int ar = idx >> 4, ak = idx & 15;
      const int row = m0 + ar;
      AsT[ak][ar] = (row < N_ANCHOR) ? q[row * CDIM + k0 + ak] : 0.0f;
    }
    #pragma unroll
    for (int i = 0; i < 4; ++i) {
      const int idx = tid + i * 256;
      const int br = idx >> 6, bc = idx & 63;
      Bs[br][bc] = wfc_w[(size_t)(k0 + br) * NW + n0 + bc];
    }
    __syncthreads();
    #pragma unroll
    for (int kk = 0; kk < 16; ++kk) {
      const float4 av = *(const float4*)&AsT[kk][ty * 4];
      const float4 bv = *(const float4*)&Bs[kk][tx * 4];
      acc[0][0] += av.x * bv.x; acc[0][1] += av.x * bv.y;
      acc[0][2] += av.x * bv.z; acc[0][3] += av.x * bv.w;
      acc[1][0] += av.y * bv.x; acc[1][1] += av.y * bv.y;
      acc[1][2] += av.y * bv.z; acc[1][3] += av.y * bv.w;
      acc[2][0] += av.z * bv.x; acc[2][1] += av.z * bv.y;
      acc[2][2] += av.z * bv.z; acc[2][3] += av.z * bv.w;
      acc[3][0] += av.w * bv.x; acc[3][1] += av.w * bv.y;
      acc[3][2] += av.w * bv.z; acc[3][3] += av.w * bv.w;
    }
    __syncthreads();
  }

  const int col = n0 + tx * 4;
  const float4 bias = *(const float4*)&wfc_b[col];
  #pragma unroll
  for (int i = 0; i < 4; ++i) {
    const int row = m0 + ty * 4 + i;
    if (row < N_ANCHOR) {
      float4 o;
      o.x = acc[i][0] + bias.x; o.y = acc[i][1] + bias.y;
      o.z = acc[i][2] + bias.z; o.w = acc[i][3] + bias.w;
      *(float4*)&raw[(size_t)row * NW + col] = o;
    }
  }
}

// ---------------------------------------------------------------------------
// Kernel 2c: per-(anchor,group) softmax over 312 entries, in place.
// grid = 900, block = 256 (8 groups x 32 lanes).
// ---------------------------------------------------------------------------
__global__ __launch_bounds__(256) void k_softmax(float* __restrict__ w) {
  const int n = blockIdx.x, t = threadIdx.x;
  __shared__ float row[NW];
  __shared__ float mx_s[NUM_GROUPS], inv_s[NUM_GROUPS];
  for (int j = t; j < NW; j += 256) row[j] = w[(size_t)n * NW + j];
  __syncthreads();
  const int g = t >> 5, lane = t & 31;
  float m = -1e30f;
  for (int i = lane; i < NI; i += 32) m = fmaxf(m, row[i * NUM_GROUPS + g]);
  #pragma unroll
  for (int o = 16; o > 0; o >>= 1) m = fmaxf(m, __shfl_down(m, o, 32));
  m = __shfl(m, 0, 32);
  float s = 0.0f;
  for (int i = lane; i < NI; i += 32) s += expf(row[i * NUM_GROUPS + g] - m);
  #pragma unroll
  for (int o = 16; o > 0; o >>= 1) s += __shfl_down(s, o, 32);
  if (lane == 0) { mx_s[g] = m; inv_s[g] = 1.0f / s; }
  __syncthreads();
  for (int j = t; j < NW; j += 256) {
    const int gg = j & 7;
    w[(size_t)n * NW + j] = expf(row[j] - mx_s[gg]) * inv_s[gg];
  }
}

// ---------------------------------------------------------------------------
// Kernel 3a: zero agg.
// ---------------------------------------------------------------------------
__global__ void k_zero(float* __restrict__ p, int n) {
  const int i = blockIdx.x * 256 + threadIdx.x;
  if (i < n) p[i] = 0.0f;
}

// ---------------------------------------------------------------------------
// Kernel 3b: fused bilinear sampling + weighted aggregation, split by camera.
// grid = (900, 6), block = 256 (thread = channel). atomicAdd into agg.
// ---------------------------------------------------------------------------
__global__ __launch_bounds__(256) void k_sample(
    const float* __restrict__ feature,
    const int* __restrict__ spatial_shapes, const int* __restrict__ level_start,
    const float* __restrict__ pts, const float* __restrict__ valid,
    const float* __restrict__ w, float* __restrict__ agg) {
  const int n = blockIdx.x;
  const int cam = blockIdx.y;
  const int t = threadIdx.x;
  const int g = t >> 5;
  __shared__ float w_s[NUM_LEVELS * NUM_PTS * NUM_GROUPS];  // 416
  __shared__ float uv_s[NUM_PTS][2];
  __shared__ float val_s[NUM_PTS];
  __shared__ int shp[NUM_LEVELS][2];
  __shared__ int lst[NUM_LEVELS];
  __shared__ int any_valid;

  if (t < NUM_PTS) {
    const int o = (n * NUM_CAMS + cam) * NUM_PTS + t;
    uv_s[t][0] = pts[o * 2 + 0];
    uv_s[t][1] = pts[o * 2 + 1];
    val_s[t] = valid[o];
  }
  if (t == 0) any_valid = 0;
  if (t < NUM_LEVELS) {
    shp[t][0] = spatial_shapes[t * 2 + 0];
    shp[t][1] = spatial_shapes[t * 2 + 1];
    lst[t] = level_start[t];
  }
  __syncthreads();
  if (t < NUM_PTS && val_s[t] != 0.0f) any_valid = 1;
  __syncthreads();
  if (!any_valid) return;

  for (int j = t; j < 416; j += 256)
    w_s[j] = w[(size_t)n * NW + cam * 416 + j];
  __syncthreads();

  float acc = 0.0f;
  const float* fcam = feature + (size_t)cam * SUM_HW * CDIM;
  for (int p = 0; p < NUM_PTS; ++p) {
    if (val_s[p] == 0.0f) continue;   // wave-uniform
    const float u = uv_s[p][0], v = uv_s[p][1];
    #pragma unroll
    for (int l = 0; l < NUM_LEVELS; ++l) {
      const int H = shp[l][0], W = shp[l][1], st = lst[l];
      const float x = u * (float)W - 0.5f;
      const float y = v * (float)H - 0.5f;
      const float x0f = floorf(x), y0f = floorf(y);
      const int x0 = (int)x0f, y0 = (int)y0f;
      const float wx = x - x0f, wy = y - y0f;
      const float wgt = w_s[(l * NUM_PTS + p) * 8 + g];
      const bool xin0 = (x0 >= 0) && (x0 < W);
      const bool xin1 = (x0 + 1 >= 0) && (x0 + 1 < W);
      const bool yin0 = (y0 >= 0) && (y0 < H);
      const bool yin1 = (y0 + 1 >= 0) && (y0 + 1 < H);
      const float c00 = wgt * (1.0f - wx) * (1.0f - wy);
      const float c10 = wgt * wx * (1.0f - wy);
      const float c01 = wgt * (1.0f - wx) * wy;
      const float c11 = wgt * wx * wy;
      const float* base = fcam + (size_t)st * CDIM + t;
      if (xin0 && yin0) acc += c00 * base[(size_t)(y0 * W + x0) * CDIM];
      if (xin1 && yin0) acc += c10 * base[(size_t)(y0 * W + x0 + 1) * CDIM];
      if (xin0 && yin1) acc += c01 * base[(size_t)((y0 + 1) * W + x0) * CDIM];
      if (xin1 && yin1) acc += c11 * base[(size_t)((y0 + 1) * W + x0 + 1) * CDIM];
    }
  }
  if (acc != 0.0f) atomicAdd(&agg[(size_t)n * CDIM + t], acc);
}

// ---------------------------------------------------------------------------
// Kernel 4: out = inst + agg @ out_w + out_b.  grid = 900, block = 256
// ---------------------------------------------------------------------------
__global__ __launch_bounds__(256) void k_out(
    const float* __restrict__ inst, const float* __restrict__ agg,
    const float* __restrict__ out_w, const float* __restrict__ out_b,
    float* __restrict__ out) {
  const int n = blockIdx.x, t = threadIdx.x;
  __shared__ float a_s[CDIM];
  a_s[t] = agg[(size_t)n * CDIM + t];
  __syncthreads();
  float s = out_b[t] + inst[(size_t)n * CDIM + t];
  for (int k = 0; k < CDIM; ++k) s += a_s[k] * out_w[k * CDIM + t];
  out[(size_t)n * CDIM + t] = s;
}

// ---------------------------------------------------------------------------
extern "C" void kernel_launch(void* const* d_in, const int* in_sizes, int n_in,
                              void* d_out, int out_size, void* d_ws, size_t ws_size,
                              hipStream_t stream) {
  const float* inst           = (const float*)d_in[0];
  const float* anchor         = (const float*)d_in[1];
  const float* feature        = (const float*)d_in[3];
  const int*   spatial_shapes = (const int*)d_in[4];
  const int*   level_start    = (const int*)d_in[5];
  const float* l2i            = (const float*)d_in[6];
  const float* image_wh       = (const float*)d_in[7];
  const float* enc_w          = (const float*)d_in[8];
  const float* enc_b          = (const float*)d_in[9];
  const float* kp_fixed       = (const float*)d_in[10];
  const float* kp_w           = (const float*)d_in[11];
  const float* kp_b           = (const float*)d_in[12];
  const float* wfc_w          = (const float*)d_in[13];
  const float* wfc_b          = (const float*)d_in[14];
  const float* out_w          = (const float*)d_in[15];
  const float* out_b          = (const float*)d_in[16];

  float* ws    = (float*)d_ws;
  float* pts   = ws;                                          // 900*78*2
  float* valid = pts + N_ANCHOR * NUM_CAMS * NUM_PTS * 2;     // 900*78
  float* qbuf  = valid + N_ANCHOR * NUM_CAMS * NUM_PTS;       // 900*256
  float* wbuf  = qbuf + N_ANCHOR * CDIM;                      // 900*2496
  float* agg   = wbuf + (size_t)N_ANCHOR * NW;                // 900*256

  k_prep<<<N_ANCHOR, 128, 0, stream>>>(inst, anchor, l2i, image_wh,
                                       kp_fixed, kp_w, kp_b, pts, valid);
  k_embed<<<N_ANCHOR, 256, 0, stream>>>(inst, anchor, enc_w, enc_b, qbuf);
  k_wgemm<<<dim3(NW / 64, (N_ANCHOR + 63) / 64), 256, 0, stream>>>(
      qbuf, wfc_w, wfc_b, wbuf);
  k_softmax<<<N_ANCHOR, 256, 0, stream>>>(wbuf);
  k_zero<<<(N_ANCHOR * CDIM + 255) / 256, 256, 0, stream>>>(agg, N_ANCHOR * CDIM);
  k_sample<<<dim3(N_ANCHOR, NUM_CAMS), 256, 0, stream>>>(
      feature, spatial_shapes, level_start, pts, valid, wbuf, agg);
  k_out<<<N_ANCHOR, 256, 0, stream>>>(inst, agg, out_w, out_b, (float*)d_out);
}

// Round 3
// 252.021 us; speedup vs baseline: 2.9857x; 1.2476x over previous
//
#include <hip/hip_runtime.h>
#include <math.h>

#define N_ANCHOR   900
#define NUM_CAMS   6
#define CDIM       256
#define NUM_LEVELS 4
#define NUM_FIXED  7
#define NUM_LEARN  6
#define NUM_PTS    13
#define NUM_GROUPS 8
#define NW         2496   // NUM_CAMS*NUM_LEVELS*NUM_PTS*NUM_GROUPS
#define NI         312    // NUM_CAMS*NUM_LEVELS*NUM_PTS (softmax axis)
#define SUM_HW     14960

// ---------------------------------------------------------------------------
// Kernel 1: keypoints + camera projection.  grid = 900, block = 128
// ---------------------------------------------------------------------------
__global__ __launch_bounds__(128) void k_prep(
    const float* __restrict__ inst, const float* __restrict__ anchor,
    const float* __restrict__ l2i, const float* __restrict__ image_wh,
    const float* __restrict__ kp_fixed, const float* __restrict__ kp_w,
    const float* __restrict__ kp_b,
    float* __restrict__ pts_out, float* __restrict__ valid_out) {
  const int n = blockIdx.x;
  const int t = threadIdx.x;
  __shared__ float anc[11];
  __shared__ float learn[NUM_LEARN * 3];
  __shared__ float kps[NUM_PTS][3];
  __shared__ float ins[CDIM];

  ins[t] = inst[n * CDIM + t];
  ins[t + 128] = inst[n * CDIM + t + 128];
  if (t < 11) anc[t] = anchor[n * 11 + t];
  __syncthreads();
  if (t < NUM_LEARN * 3) {
    float s = kp_b[t];
    for (int k = 0; k < CDIM; ++k) s += ins[k] * kp_w[k * (NUM_LEARN * 3) + t];
    learn[t] = s;
  }
  __syncthreads();

  if (t < NUM_PTS) {
    const float sx = expf(anc[3]), sy = expf(anc[4]), sz = expf(anc[5]);
    float ox, oy, oz;
    if (t < NUM_FIXED) {
      ox = kp_fixed[t * 3 + 0]; oy = kp_fixed[t * 3 + 1]; oz = kp_fixed[t * 3 + 2];
    } else {
      const int j = (t - NUM_FIXED) * 3;
      ox = learn[j + 0]; oy = learn[j + 1]; oz = learn[j + 2];
    }
    ox *= sx; oy *= sy; oz *= sz;
    const float sn = anc[6], cs = anc[7];
    kps[t][0] = cs * ox - sn * oy + anc[0];
    kps[t][1] = sn * ox + cs * oy + anc[1];
    kps[t][2] = oz + anc[2];
  }
  __syncthreads();

  if (t < NUM_CAMS * NUM_PTS) {
    const int cam = t / NUM_PTS, p = t % NUM_PTS;
    const float* M = l2i + cam * 16;
    const float kx = kps[p][0], ky = kps[p][1], kz = kps[p][2];
    const float px = M[0] * kx + M[1] * ky + M[2]  * kz + M[3];
    const float py = M[4] * kx + M[5] * ky + M[6]  * kz + M[7];
    const float pz = M[8] * kx + M[9] * ky + M[10] * kz + M[11];
    const float d = fmaxf(pz, 1e-5f);
    const float u = (px / d) / image_wh[cam * 2 + 0];
    const float v = (py / d) / image_wh[cam * 2 + 1];
    const int o = n * NUM_CAMS * NUM_PTS + t;
    pts_out[o * 2 + 0] = u;
    pts_out[o * 2 + 1] = v;
    valid_out[o] = (pz > 1e-5f) ? 1.0f : 0.0f;
  }
}

// ---------------------------------------------------------------------------
// Kernel 2a: q = inst + anchor @ enc_w + enc_b.  grid = 900, block = 256
// ---------------------------------------------------------------------------
__global__ __launch_bounds__(256) void k_embed(
    const float* __restrict__ inst, const float* __restrict__ anchor,
    const float* __restrict__ enc_w, const float* __restrict__ enc_b,
    float* __restrict__ q) {
  const int n = blockIdx.x, t = threadIdx.x;
  float s = enc_b[t] + inst[n * CDIM + t];
  #pragma unroll
  for (int k = 0; k < 11; ++k) s += anchor[n * 11 + k] * enc_w[k * CDIM + t];
  q[n * CDIM + t] = s;
}

// ---------------------------------------------------------------------------
// Kernel 2b: tiled GEMM  raw[900][2496] = q[900][256] @ wfc_w[256][2496] + b
// 64x64 tile, 4x4 per thread, K-tile 16, float4 staging. grid=(39,15), 256 thr
// ---------------------------------------------------------------------------
__global__ __launch_bounds__(256) void k_wgemm(
    const float* __restrict__ q, const float* __restrict__ wfc_w,
    const float* __restrict__ wfc_b, float* __restrict__ raw) {
  const int tid = threadIdx.x;
  const int n0 = blockIdx.x * 64;
  const int m0 = blockIdx.y * 64;
  const int tx = tid & 15, ty = tid >> 4;
  const int ar = tid >> 2, av4 = tid & 3;       // A staging: row, k-group
  const int br = tid >> 4, bc4 = (tid & 15) * 4;// B staging: k-row, col
  __shared__ float AsT[16][68];
  __shared__ float Bs[16][64];
  float acc[4][4] = {{0.f}};

  const int arow = m0 + ar;
  for (int k0 = 0; k0 < CDIM; k0 += 16) {
    float4 a4 = make_float4(0.f, 0.f, 0.f, 0.f);
    if (arow < N_ANCHOR) a4 = *(const float4*)&q[arow * CDIM + k0 + av4 * 4];
    const float4 b4 = *(const float4*)&wfc_w[(size_t)(k0 + br) * NW + n0 + bc4];
    AsT[av4 * 4 + 0][ar] = a4.x;
    AsT[av4 * 4 + 1][ar] = a4.y;
    AsT[av4 * 4 + 2][ar] = a4.z;
    AsT[av4 * 4 + 3][ar] = a4.w;
    *(float4*)&Bs[br][bc4] = b4;
    __syncthreads();
    #pragma unroll
    for (int kk = 0; kk < 16; ++kk) {
      const float4 av = *(const float4*)&AsT[kk][ty * 4];
      const float4 bv = *(const float4*)&Bs[kk][tx * 4];
      acc[0][0] += av.x * bv.x; acc[0][1] += av.x * bv.y;
      acc[0][2] += av.x * bv.z; acc[0][3] += av.x * bv.w;
      acc[1][0] += av.y * bv.x; acc[1][1] += av.y * bv.y;
      acc[1][2] += av.y * bv.z; acc[1][3] += av.y * bv.w;
      acc[2][0] += av.z * bv.x; acc[2][1] += av.z * bv.y;
      acc[2][2] += av.z * bv.z; acc[2][3] += av.z * bv.w;
      acc[3][0] += av.w * bv.x; acc[3][1] += av.w * bv.y;
      acc[3][2] += av.w * bv.z; acc[3][3] += av.w * bv.w;
    }
    __syncthreads();
  }

  const int col = n0 + tx * 4;
  const float4 bias = *(const float4*)&wfc_b[col];
  #pragma unroll
  for (int i = 0; i < 4; ++i) {
    const int row = m0 + ty * 4 + i;
    if (row < N_ANCHOR) {
      float4 o;
      o.x = acc[i][0] + bias.x; o.y = acc[i][1] + bias.y;
      o.z = acc[i][2] + bias.z; o.w = acc[i][3] + bias.w;
      *(float4*)&raw[(size_t)row * NW + col] = o;
    }
  }
}

// ---------------------------------------------------------------------------
// Kernel 2c: softmax stats per (anchor, group): max and 1/sum over 312.
// grid = 900, block = 256 (8 groups x 32 lanes). stats[n][0..7]=max, [8..15]=inv
// ---------------------------------------------------------------------------
__global__ __launch_bounds__(256) void k_smstats(
    const float* __restrict__ raw, float* __restrict__ stats) {
  const int n = blockIdx.x, t = threadIdx.x;
  const int g = t >> 5, lane = t & 31;
  const float* r = raw + (size_t)n * NW;
  float m = -1e30f;
  for (int i = lane; i < NI; i += 32) m = fmaxf(m, r[i * NUM_GROUPS + g]);
  #pragma unroll
  for (int o = 16; o > 0; o >>= 1) m = fmaxf(m, __shfl_down(m, o, 32));
  m = __shfl(m, 0, 32);
  float s = 0.0f;
  for (int i = lane; i < NI; i += 32) s += expf(r[i * NUM_GROUPS + g] - m);
  #pragma unroll
  for (int o = 16; o > 0; o >>= 1) s += __shfl_down(s, o, 32);
  if (lane == 0) {
    stats[n * 16 + g] = m;
    stats[n * 16 + 8 + g] = 1.0f / s;
  }
}

// ---------------------------------------------------------------------------
// Kernel 3: corner-parallel bilinear sampling + weighted aggregation.
// grid = (900, 6), block = 256. wave q = corner, lane ci = 4-channel chunk.
// Writes per-cam slice agg[n][cam][256] (no atomics).
// ---------------------------------------------------------------------------
__global__ __launch_bounds__(256) void k_sample(
    const float* __restrict__ feature,
    const int* __restrict__ spatial_shapes, const int* __restrict__ level_start,
    const float* __restrict__ pts, const float* __restrict__ valid,
    const float* __restrict__ raw, const float* __restrict__ stats,
    float* __restrict__ agg) {
  const int n = blockIdx.x;
  const int cam = blockIdx.y;
  const int t = threadIdx.x;
  const int q = t >> 6;          // corner (one per wave)
  const int ci = t & 63;         // channel chunk: channels 4*ci .. 4*ci+3
  const int g = ci >> 3;         // group of this chunk
  __shared__ float w_s[NUM_LEVELS * NUM_PTS * NUM_GROUPS];  // 416
  __shared__ float uv_s[NUM_PTS][2];
  __shared__ float val_s[NUM_PTS];
  __shared__ float mx_s[NUM_GROUPS], inv_s[NUM_GROUPS];
  __shared__ int shp[NUM_LEVELS][2];
  __shared__ int lst[NUM_LEVELS];
  __shared__ int any_valid;
  __shared__ float4 red[256];

  if (t < NUM_PTS) {
    const int o = (n * NUM_CAMS + cam) * NUM_PTS + t;
    uv_s[t][0] = pts[o * 2 + 0];
    uv_s[t][1] = pts[o * 2 + 1];
    val_s[t] = valid[o];
  }
  if (t < NUM_GROUPS) {
    mx_s[t]  = stats[n * 16 + t];
    inv_s[t] = stats[n * 16 + 8 + t];
  }
  if (t < NUM_LEVELS) {
    shp[t][0] = spatial_shapes[t * 2 + 0];
    shp[t][1] = spatial_shapes[t * 2 + 1];
    lst[t] = level_start[t];
  }
  if (t == 0) any_valid = 0;
  __syncthreads();
  if (t < NUM_PTS && val_s[t] != 0.0f) any_valid = 1;
  __syncthreads();

  float* aout = agg + ((size_t)n * NUM_CAMS + cam) * CDIM;
  if (!any_valid) {
    if (t < 64) *(float4*)&aout[t * 4] = make_float4(0.f, 0.f, 0.f, 0.f);
    return;
  }

  for (int j = t; j < 416; j += 256)
    w_s[j] = expf(raw[(size_t)n * NW + cam * 416 + j] - mx_s[j & 7]) * inv_s[j & 7];
  __syncthreads();

  const int dx = q & 1, dy = q >> 1;
  float4 acc = make_float4(0.f, 0.f, 0.f, 0.f);
  const float* fcam = feature + (size_t)cam * SUM_HW * CDIM;
  for (int p = 0; p < NUM_PTS; ++p) {
    if (val_s[p] == 0.0f) continue;   // block-uniform
    const float u = uv_s[p][0], v = uv_s[p][1];
    #pragma unroll
    for (int l = 0; l < NUM_LEVELS; ++l) {
      const int H = shp[l][0], W = shp[l][1], st = lst[l];
      const float x = u * (float)W - 0.5f;
      const float y = v * (float)H - 0.5f;
      const float x0f = floorf(x), y0f = floorf(y);
      const float wx = x - x0f, wy = y - y0f;
      const int xx = (int)x0f + dx;
      const int yy = (int)y0f + dy;
      if (xx >= 0 && xx < W && yy >= 0 && yy < H) {   // wave-uniform
        const float cw = w_s[(l * NUM_PTS + p) * 8 + g]
                       * (dx ? wx : 1.0f - wx) * (dy ? wy : 1.0f - wy);
        const float4 f = *(const float4*)&fcam[(size_t)(st + yy * W + xx) * CDIM + ci * 4];
        acc.x += cw * f.x; acc.y += cw * f.y;
        acc.z += cw * f.z; acc.w += cw * f.w;
      }
    }
  }
  red[t] = acc;
  __syncthreads();
  if (t < 64) {
    float4 s = red[t];
    const float4 b1 = red[t + 64], b2 = red[t + 128], b3 = red[t + 192];
    s.x += b1.x + b2.x + b3.x;
    s.y += b1.y + b2.y + b3.y;
    s.z += b1.z + b2.z + b3.z;
    s.w += b1.w + b2.w + b3.w;
    *(float4*)&aout[t * 4] = s;
  }
}

// ---------------------------------------------------------------------------
// Kernel 4: out = inst + (sum_cam agg) @ out_w + out_b.  grid = 450, block 256
// ---------------------------------------------------------------------------
__global__ __launch_bounds__(256) void k_out(
    const float* __restrict__ inst, const float* __restrict__ agg,
    const float* __restrict__ out_w, const float* __restrict__ out_b,
    float* __restrict__ out) {
  const int n0 = blockIdx.x * 2, t = threadIdx.x;
  __shared__ float a_s[2][CDIM];
  #pragma unroll
  for (int a = 0; a < 2; ++a) {
    float s = 0.0f;
    #pragma unroll
    for (int cam = 0; cam < NUM_CAMS; ++cam)
      s += agg[((size_t)(n0 + a) * NUM_CAMS + cam) * CDIM + t];
    a_s[a][t] = s;
  }
  __syncthreads();
  float acc0 = out_b[t] + inst[(size_t)n0 * CDIM + t];
  float acc1 = out_b[t] + inst[(size_t)(n0 + 1) * CDIM + t];
  for (int k = 0; k < CDIM; ++k) {
    const float w = out_w[k * CDIM + t];
    acc0 += a_s[0][k] * w;
    acc1 += a_s[1][k] * w;
  }
  out[(size_t)n0 * CDIM + t] = acc0;
  out[(size_t)(n0 + 1) * CDIM + t] = acc1;
}

// ---------------------------------------------------------------------------
extern "C" void kernel_launch(void* const* d_in, const int* in_sizes, int n_in,
                              void* d_out, int out_size, void* d_ws, size_t ws_size,
                              hipStream_t stream) {
  const float* inst           = (const float*)d_in[0];
  const float* anchor         = (const float*)d_in[1];
  const float* feature        = (const float*)d_in[3];
  const int*   spatial_shapes = (const int*)d_in[4];
  const int*   level_start    = (const int*)d_in[5];
  const float* l2i            = (const float*)d_in[6];
  const float* image_wh       = (const float*)d_in[7];
  const float* enc_w          = (const float*)d_in[8];
  const float* enc_b          = (const float*)d_in[9];
  const float* kp_fixed       = (const float*)d_in[10];
  const float* kp_w           = (const float*)d_in[11];
  const float* kp_b           = (const float*)d_in[12];
  const float* wfc_w          = (const float*)d_in[13];
  const float* wfc_b          = (const float*)d_in[14];
  const float* out_w          = (const float*)d_in[15];
  const float* out_b          = (const float*)d_in[16];

  float* ws    = (float*)d_ws;
  float* pts   = ws;                                          // 900*78*2
  float* valid = pts + N_ANCHOR * NUM_CAMS * NUM_PTS * 2;     // 900*78
  float* qbuf  = valid + N_ANCHOR * NUM_CAMS * NUM_PTS;       // 900*256
  float* wbuf  = qbuf + N_ANCHOR * CDIM;                      // 900*2496
  float* stats = wbuf + (size_t)N_ANCHOR * NW;                // 900*16
  float* agg   = stats + N_ANCHOR * 16;                       // 900*6*256

  k_prep<<<N_ANCHOR, 128, 0, stream>>>(inst, anchor, l2i, image_wh,
                                       kp_fixed, kp_w, kp_b, pts, valid);
  k_embed<<<N_ANCHOR, 256, 0, stream>>>(inst, anchor, enc_w, enc_b, qbuf);
  k_wgemm<<<dim3(NW / 64, (N_ANCHOR + 63) / 64), 256, 0, stream>>>(
      qbuf, wfc_w, wfc_b, wbuf);
  k_smstats<<<N_ANCHOR, 256, 0, stream>>>(wbuf, stats);
  k_sample<<<dim3(N_ANCHOR, NUM_CAMS), 256, 0, stream>>>(
      feature, spatial_shapes, level_start, pts, valid, wbuf, stats, agg);
  k_out<<<N_ANCHOR / 2, 256, 0, stream>>>(inst, agg, out_w, out_b, (float*)d_out);
}